// Round 7
// baseline (1132.846 us; speedup 1.0000x reference)
//
#include <hip/hip_runtime.h>
#include <math.h>

// ---- problem constants ----
#define BATCH  32
#define NTOK   577
#define CDIM   1024
#define C3DIM  3072
#define H4DIM  4096
#define NHEAD  16
#define MROWS  (BATCH * NTOK)   // 18464
#define NPADV  584              // 577 rounded up to 8 (V^T row pad)

typedef __bf16 bf16x8 __attribute__((ext_vector_type(8)));
typedef float  f32x4  __attribute__((ext_vector_type(4)));
typedef unsigned short u16x8 __attribute__((ext_vector_type(8)));

__device__ __forceinline__ float bf2f(unsigned short u) {
    union { unsigned int i; float f; } v; v.i = ((unsigned int)u) << 16; return v.f;
}
__device__ __forceinline__ unsigned short f2bf(float f) {
    union { float f; unsigned int i; } v; v.f = f;
    unsigned int r = v.i + 0x7FFFu + ((v.i >> 16) & 1u);
    return (unsigned short)(r >> 16);
}
__device__ __forceinline__ bf16x8 ld_bf8(const unsigned short* p) {
    return __builtin_bit_cast(bf16x8, *(const u16x8*)p);
}

// async global->LDS, 16B per lane. LDS dest = wave-uniform base + lane*16.
typedef const __attribute__((address_space(1))) unsigned int* gptr_t;
typedef __attribute__((address_space(3))) unsigned int* lptr_t;
__device__ __forceinline__ void gl2lds(const void* g, const void* l) {
    __builtin_amdgcn_global_load_lds(
        (gptr_t)(unsigned long long)g,
        (lptr_t)(unsigned int)(unsigned long long)l,
        16, 0, 0);
}

// Bijective chunked XCD remap (m204). r3 verified: fc2 FETCH 674 MB -> 167 MB.
__device__ __forceinline__ int xcd_chunk_logical(int orig, int nwg) {
    int xcd = orig & 7, k = orig >> 3;
    int q = nwg >> 3, r = nwg & 7;
    int base = xcd < r ? xcd * (q + 1) : r * (q + 1) + (xcd - r) * q;
    return base + k;
}

// ---- T2 LDS swizzle for 64B rows (BK=32 bf16) ----
// Read pattern: 16 lanes (l16) read 16 consecutive rows at chunk q -> without
// swizzle only 2 bank-groups are hit (8-way conflict, 2.94x). With
// c' = c ^ ((row>>1)&3), the 16 rows map to 8 distinct 4-bank groups (2-way =
// free, m136). gl2lds writes linearly, so the permutation is applied on the
// per-lane GLOBAL source chunk (rule #21): lane fetches chunk
// (lane&3)^((lane>>3)&3); read uses chunk q^((l16>>1)&3). Involution verified:
// wave-invariant ((w*8)&3==0), bijective per row, phys = glob ^ ((row>>1)&3).
#define SW_SRC(tid)  ((((tid) & 3) ^ (((tid) >> 3) & 3)) << 3)

// Q pre-scale: Dh^-0.5 * log2(e), so softmax runs in exp2 domain
#define QSCALE 0.18033688011112042f

// GELU tanh-form in exp2 domain: max |err| vs erf-GELU ~3e-4 << bf16 noise.
__device__ __forceinline__ float gelu_f(float v) {
    float z = exp2f(v * fmaf(v * v, 0.1029432f, 2.3022082f));
    return v - v * __builtin_amdgcn_rcpf(1.0f + z);
}

// ---------------- f32 -> bf16 convert ----------------
__global__ __launch_bounds__(256) void conv_kernel(const float* __restrict__ src,
                                                   unsigned short* __restrict__ dst, int n) {
    int i = (blockIdx.x * 256 + threadIdx.x) * 4;
    if (i < n) {
        float4 v = *(const float4*)(src + i);
        dst[i]     = f2bf(v.x);
        dst[i + 1] = f2bf(v.y);
        dst[i + 2] = f2bf(v.z);
        dst[i + 3] = f2bf(v.w);
    }
}

// ---------------- LayerNorm ----------------
template<bool F32IN>
__global__ __launch_bounds__(256) void ln_kernel(
    const void* __restrict__ X,
    const float* __restrict__ w,
    const float* __restrict__ b,
    unsigned short* __restrict__ out)
{
    const int row = blockIdx.x;
    const int t = threadIdx.x;
    float vals[4]; float s = 0.f, ss = 0.f;
#pragma unroll
    for (int i = 0; i < 4; i++) {
        int c = t + i * 256;
        float v;
        if (F32IN) v = ((const float*)X)[(size_t)row * CDIM + c];
        else       v = bf2f(((const unsigned short*)X)[(size_t)row * CDIM + c]);
        vals[i] = v; s += v; ss += v * v;
    }
#pragma unroll
    for (int off = 32; off > 0; off >>= 1) { s += __shfl_xor(s, off); ss += __shfl_xor(ss, off); }
    __shared__ float red[8];
    if ((t & 63) == 0) { red[t >> 6] = s; red[4 + (t >> 6)] = ss; }
    __syncthreads();
    s  = red[0] + red[1] + red[2] + red[3];
    ss = red[4] + red[5] + red[6] + red[7];
    float mu  = s * (1.f / CDIM);
    float var = ss * (1.f / CDIM) - mu * mu;
    float rs  = rsqrtf(var + 1e-6f);
#pragma unroll
    for (int i = 0; i < 4; i++) {
        int c = t + i * 256;
        float o = (vals[i] - mu) * rs * w[c] + b[c];
        out[(size_t)row * CDIM + c] = f2bf(o);
    }
}

// ============ GEMM A: 128x128 tile, BK=32, 4 waves, depth-2 pipeline ========
// 3 LDS buffers (48 KiB, 3 blocks/CU), counted vmcnt(4) (T4), T2 swizzle,
// T5 setprio. OP=1: +bias +f32 residual, bf16 out. OP=3: +bias +bf16 residual,
// f32 out. OP=4: f32 accumulate (no bias).
template<int OP>
__global__ __launch_bounds__(256) void gemm128(
    const unsigned short* __restrict__ A,
    const unsigned short* __restrict__ W, int Wstride,
    const unsigned short* __restrict__ bias,
    const void* __restrict__ Res,
    void* __restrict__ Out,
    int K, int Nout, int ntn)
{
    __shared__ __align__(16) unsigned short Alds[3][128 * 32];
    __shared__ __align__(16) unsigned short Blds[3][128 * 32];
    const int tid  = threadIdx.x;
    const int lane = tid & 63, wave = tid >> 6;
    const int q = lane >> 4, l16 = lane & 15;
    const int wm = (wave & 1) << 6, wn = (wave >> 1) << 6;
    const int swr = (l16 >> 1) & 3;          // read-side swizzle

    const int logical = xcd_chunk_logical(blockIdx.x, gridDim.x);
    const int tileM = (logical / ntn) << 7;
    const int tileN = (logical % ntn) << 7;

    f32x4 acc[4][4];
#pragma unroll
    for (int i = 0; i < 4; i++)
#pragma unroll
        for (int j = 0; j < 4; j++) acc[i][j] = (f32x4){0.f, 0.f, 0.f, 0.f};

    const int srow = tid >> 2;               // 0..63
    const int soff = SW_SRC(tid);            // swizzled source chunk
    const unsigned short* pA[2];
    const unsigned short* pB[2];
#pragma unroll
    for (int j = 0; j < 2; j++) {
        int ra = tileM + j * 64 + srow; if (ra > MROWS - 1) ra = MROWS - 1;
        pA[j] = A + (size_t)ra * K + soff;
        pB[j] = W + (size_t)(tileN + j * 64 + srow) * Wstride + soff;
    }

    auto STAGE = [&](int buf, int k0) {   // 4 gl2lds per wave
#pragma unroll
        for (int j = 0; j < 2; j++) {
            gl2lds(pA[j] + k0, &Alds[buf][j * 2048 + wave * 512]);
            gl2lds(pB[j] + k0, &Blds[buf][j * 2048 + wave * 512]);
        }
    };

    auto COMPUTE = [&](int buf) {
        bf16x8 af[4], bfr[4];
#pragma unroll
        for (int mi = 0; mi < 4; mi++)
            af[mi]  = ld_bf8(&Alds[buf][(wm + mi * 16 + l16) * 32 + ((q ^ swr) << 3)]);
#pragma unroll
        for (int ni = 0; ni < 4; ni++)
            bfr[ni] = ld_bf8(&Blds[buf][(wn + ni * 16 + l16) * 32 + ((q ^ swr) << 3)]);
        __builtin_amdgcn_s_setprio(1);
#pragma unroll
        for (int mi = 0; mi < 4; mi++)
#pragma unroll
            for (int ni = 0; ni < 4; ni++)
                acc[mi][ni] = __builtin_amdgcn_mfma_f32_16x16x32_bf16(af[mi], bfr[ni], acc[mi][ni], 0, 0, 0);
        __builtin_amdgcn_s_setprio(0);
    };

    const int NT = K >> 5;
    STAGE(0, 0);
    STAGE(1, 32);
    int t = 0;
    for (; t < NT - 1; ++t) {
        asm volatile("s_waitcnt vmcnt(4)" ::: "memory");   // t's landed; t+1 in flight
        __builtin_amdgcn_s_barrier();
        __builtin_amdgcn_sched_barrier(0);
        if (t + 2 < NT) STAGE((t + 2) % 3, (t + 2) << 5);
        COMPUTE(t % 3);
    }
    asm volatile("s_waitcnt vmcnt(0)" ::: "memory");
    __builtin_amdgcn_s_barrier();
    __builtin_amdgcn_sched_barrier(0);
    COMPUTE(t % 3);

#pragma unroll
    for (int mi = 0; mi < 4; mi++) {
#pragma unroll
        for (int r = 0; r < 4; r++) {
            int row = tileM + wm + mi * 16 + q * 4 + r;
            if (row >= MROWS) continue;
#pragma unroll
            for (int ni = 0; ni < 4; ni++) {
                int col = tileN + wn + ni * 16 + l16;
                size_t oidx = (size_t)row * Nout + col;
                float v = acc[mi][ni][r];
                if constexpr (OP != 4) v += bf2f(bias[col]);
                if constexpr (OP == 1) {
                    v += ((const float*)Res)[oidx];
                    ((unsigned short*)Out)[oidx] = f2bf(v);
                } else if constexpr (OP == 3) {
                    v += bf2f(((const unsigned short*)Res)[oidx]);
                    ((float*)Out)[oidx] = v;
                } else {
                    ((float*)Out)[oidx] += v;
                }
            }
        }
    }
}

// ============ GEMM B: 256x256 tile, BK=32, 8 waves, depth-2 pipeline ========
// 3 LDS buffers (96 KiB, 1 block/CU), counted vmcnt(4), T2 swizzle, T5 setprio,
// M-banded logical order (W-tile L2 reuse within band of 4 M-panels).
// OP=0: +bias, qkv split-scatter. OP=2: +bias, GELU, bf16 out (fc1).
template<int OP>
__global__ __launch_bounds__(512, 2) void gemm256(
    const unsigned short* __restrict__ A,
    const unsigned short* __restrict__ W, int Wstride,
    const unsigned short* __restrict__ bias,
    void* __restrict__ Out,
    void* __restrict__ Out2,
    void* __restrict__ Out3,
    int K, int Nout, int ntn)
{
    __shared__ __align__(16) unsigned short Alds[3][256 * 32];
    __shared__ __align__(16) unsigned short Blds[3][256 * 32];

    const int tid  = threadIdx.x;
    const int lane = tid & 63, wave = tid >> 6;
    const int q = lane >> 4, l16 = lane & 15;
    const int wm = (wave >> 2) << 7;   // 0 or 128 (M half)
    const int wn = (wave & 3) << 6;    // 0/64/128/192 (N quarter)
    const int swr = (l16 >> 1) & 3;

    // banded decode: band of 4 M-panels, m fastest within band (bijective incl. tail)
    const int logical = xcd_chunk_logical(blockIdx.x, gridDim.x);
    const int ntm = gridDim.x / ntn;
    const int per_band = ntn << 2;
    const int band = logical / per_band;
    const int rb = logical % per_band;
    const int mb0 = band << 2;
    const int rows = (ntm - mb0) < 4 ? (ntm - mb0) : 4;
    const int tileN = (rb / rows) << 8;
    const int tileM = (mb0 + rb % rows) << 8;

    f32x4 acc[8][4];
#pragma unroll
    for (int i = 0; i < 8; i++)
#pragma unroll
        for (int j = 0; j < 4; j++) acc[i][j] = (f32x4){0.f, 0.f, 0.f, 0.f};

    const int srow = tid >> 2;          // 0..127
    const int soff = SW_SRC(tid);       // swizzled source chunk
    const unsigned short* pA[2];
    const unsigned short* pB[2];
#pragma unroll
    for (int j = 0; j < 2; j++) {
        int ra = tileM + j * 128 + srow; if (ra > MROWS - 1) ra = MROWS - 1;
        pA[j] = A + (size_t)ra * K + soff;
        pB[j] = W + (size_t)(tileN + j * 128 + srow) * Wstride + soff;
    }

    auto STAGE = [&](int buf, int k0) {   // 4 gl2lds per wave
#pragma unroll
        for (int j = 0; j < 2; j++) {
            gl2lds(pA[j] + k0, &Alds[buf][j * 4096 + wave * 512]);
            gl2lds(pB[j] + k0, &Blds[buf][j * 4096 + wave * 512]);
        }
    };

    auto COMPUTE = [&](int buf) {
        bf16x8 af[8], bfr[4];
#pragma unroll
        for (int mi = 0; mi < 8; mi++)
            af[mi] = ld_bf8(&Alds[buf][(wm + mi * 16 + l16) * 32 + ((q ^ swr) << 3)]);
#pragma unroll
        for (int ni = 0; ni < 4; ni++)
            bfr[ni] = ld_bf8(&Blds[buf][(wn + ni * 16 + l16) * 32 + ((q ^ swr) << 3)]);
        __builtin_amdgcn_s_setprio(1);
#pragma unroll
        for (int mi = 0; mi < 8; mi++)
#pragma unroll
            for (int ni = 0; ni < 4; ni++)
                acc[mi][ni] = __builtin_amdgcn_mfma_f32_16x16x32_bf16(af[mi], bfr[ni], acc[mi][ni], 0, 0, 0);
        __builtin_amdgcn_s_setprio(0);
    };

    const int NT = K >> 5;
    STAGE(0, 0);
    STAGE(1, 32);
    int t = 0;
    for (; t < NT - 1; ++t) {
        asm volatile("s_waitcnt vmcnt(4)" ::: "memory");
        __builtin_amdgcn_s_barrier();
        __builtin_amdgcn_sched_barrier(0);
        if (t + 2 < NT) STAGE((t + 2) % 3, (t + 2) << 5);
        COMPUTE(t % 3);
    }
    asm volatile("s_waitcnt vmcnt(0)" ::: "memory");
    __builtin_amdgcn_s_barrier();
    __builtin_amdgcn_sched_barrier(0);
    COMPUTE(t % 3);

#pragma unroll
    for (int mi = 0; mi < 8; mi++) {
#pragma unroll
        for (int r = 0; r < 4; r++) {
            int row = tileM + wm + mi * 16 + q * 4 + r;
            if (row >= MROWS) continue;
            unsigned int bb = 0, nn = 0;
            if constexpr (OP == 0) {
                bb = ((unsigned int)row * 58154u) >> 25;   // row/577, exact for row<78766
                nn = (unsigned int)row - bb * 577u;
            }
#pragma unroll
            for (int ni = 0; ni < 4; ni++) {
                int col = tileN + wn + ni * 16 + l16;
                size_t oidx = (size_t)row * Nout + col;
                float v = acc[mi][ni][r] + bf2f(bias[col]);
                if constexpr (OP == 0) {
                    int s = col >> 10, h = (col >> 6) & 15, d = col & 63;
                    size_t bh = (size_t)(bb * 16 + h);
                    if (s == 0)      ((unsigned short*)Out )[(bh * NTOK + nn) * 64 + d] = f2bf(v * QSCALE);
                    else if (s == 1) ((unsigned short*)Out2)[(bh * NTOK + nn) * 64 + d] = f2bf(v);
                    else             ((unsigned short*)Out3)[(bh * 64 + d) * NPADV + nn] = f2bf(v);
                } else {  // OP == 2
                    ((unsigned short*)Out)[oidx] = f2bf(gelu_f(v));
                }
            }
        }
    }
}

// ---------------- Flash attention, no-max unnormalized softmax ----------------
__global__ __launch_bounds__(256) void attn_kernel(
    const unsigned short* __restrict__ Qb,
    const unsigned short* __restrict__ Kb,
    const unsigned short* __restrict__ Vt,
    unsigned short* __restrict__ o)
{
    const int flat = blockIdx.x;
    const int x8 = flat & 7;
    const int g = flat >> 3;
    const int qt = g % 10;
    const int bh = (g / 10) * 8 + x8;      // b*16 + h
    const int q0 = qt * 64;
    const int tid = threadIdx.x;
    const int wv = tid >> 6, lane = tid & 63;
    const int qd = lane >> 4, l16 = lane & 15;

    __shared__ __align__(16) unsigned short Ps[4][16 * 72];

    const unsigned short* Qh = Qb + (size_t)bh * NTOK * 64;
    const unsigned short* Kh = Kb + (size_t)bh * NTOK * 64;
    const unsigned short* Vh = Vt + (size_t)bh * 64 * NPADV;

    int qrow = q0 + wv * 16 + l16;
    int qr = qrow < NTOK ? qrow : NTOK - 1;
    bf16x8 qf0 = ld_bf8(Qh + (size_t)qr * 64 + qd * 8);
    bf16x8 qf1 = ld_bf8(Qh + (size_t)qr * 64 + 32 + qd * 8);

    float lsum[4];
    f32x4 Oacc[4];
#pragma unroll
    for (int r = 0; r < 4; r++) lsum[r] = 0.f;
#pragma unroll
    for (int ni = 0; ni < 4; ni++) Oacc[ni] = (f32x4){0.f, 0.f, 0.f, 0.f};

    for (int kt = 0; kt < 10; kt++) {
        const int k0 = kt * 64;
        const bool tail = (kt == 9);
        f32x4 sacc[4];
#pragma unroll
        for (int ni = 0; ni < 4; ni++) sacc[ni] = (f32x4){0.f, 0.f, 0.f, 0.f};
#pragma unroll
        for (int ni = 0; ni < 4; ni++) {
            int krow = k0 + ni * 16 + l16;
            if (krow > NTOK - 1) krow = NTOK - 1;
            const unsigned short* kp = Kh + (size_t)krow * 64 + qd * 8;
            bf16x8 b0 = ld_bf8(kp);
            bf16x8 b1 = ld_bf8(kp + 32);
            sacc[ni] = __builtin_amdgcn_mfma_f32_16x16x32_bf16(qf0, b0, sacc[ni], 0, 0, 0);
            sacc[ni] = __builtin_amdgcn_mfma_f32_16x16x32_bf16(qf1, b1, sacc[ni], 0, 0, 0);
        }

#pragma unroll
        for (int r = 0; r < 4; r++) {
#pragma unroll
            for (int ni = 0; ni < 4; ni++) {
                float pv = exp2f(sacc[ni][r]);
                if (tail && (k0 + ni * 16 + l16 >= NTOK)) pv = 0.f;
                lsum[r] += pv;
                Ps[wv][(qd * 4 + r) * 72 + ni * 16 + l16] = f2bf(pv);
            }
        }

#pragma unroll
        for (int kk = 0; kk < 2; kk++) {
            bf16x8 a = ld_bf8(&Ps[wv][l16 * 72 + kk * 32 + qd * 8]);
            int kchunk = k0 + kk * 32 + qd * 8;
            if (kchunk > NTOK - 1) kchunk = NTOK - 1;  // clamped chunks have P==0
#pragma unroll
            for (int ni = 0; ni < 4; ni++) {
                bf16x8 bb = ld_bf8(Vh + (size_t)(ni * 16 + l16) * NPADV + kchunk);
                Oacc[ni] = __builtin_amdgcn_mfma_f32_16x16x32_bf16(a, bb, Oacc[ni], 0, 0, 0);
            }
        }
    }

#pragma unroll
    for (int r = 0; r < 4; r++)
#pragma unroll
        for (int off = 8; off > 0; off >>= 1) lsum[r] += __shfl_xor(lsum[r], off);

    const int b = bh >> 4, h = bh & 15;
#pragma unroll
    for (int r = 0; r < 4; r++) {
        int gq = q0 + wv * 16 + qd * 4 + r;
        if (gq >= NTOK) continue;
        float inv = 1.0f / lsum[r];
#pragma unroll
        for (int ni = 0; ni < 4; ni++) {
            int d = ni * 16 + l16;
            o[((size_t)b * NTOK + gq) * CDIM + (size_t)h * 64 + d] = f2bf(Oacc[ni][r] * inv);
        }
    }
}

// ---------------- launch ----------------
extern "C" void kernel_launch(void* const* d_in, const int* in_sizes, int n_in,
                              void* d_out, int out_size, void* d_ws, size_t ws_size,
                              hipStream_t stream) {
    (void)in_sizes; (void)n_in; (void)out_size;
    const float* x      = (const float*)d_in[0];
    const float* ln1_w  = (const float*)d_in[1];
    const float* ln1_b  = (const float*)d_in[2];
    const float* qkv_w  = (const float*)d_in[3];
    const float* qkv_b  = (const float*)d_in[4];
    const float* proj_w = (const float*)d_in[5];
    const float* proj_b = (const float*)d_in[6];
    const float* ln2_w  = (const float*)d_in[7];
    const float* ln2_b  = (const float*)d_in[8];
    const float* fc1_w  = (const float*)d_in[9];
    const float* fc1_b  = (const float*)d_in[10];
    const float* fc2_w  = (const float*)d_in[11];
    const float* fc2_b  = (const float*)d_in[12];

    // ---- ws layout: converted weights, then big regions ----
    char* ws = (char*)d_ws;
    size_t off = 0;
    auto alloc = [&](size_t els) { void* p = ws + off; off += els * 2; return (unsigned short*)p; };
    unsigned short* qkvw_b  = alloc(3145728);
    unsigned short* projw_b = alloc(1048576);
    unsigned short* fc1w_b  = alloc(4194304);
    unsigned short* fc2w_b  = alloc(4194304);
    unsigned short* qkvb_b  = alloc(3072);
    unsigned short* projb_b = alloc(1024);
    unsigned short* fc1b_b  = alloc(4096);
    unsigned short* fc2b_b  = alloc(1024);
    off = (off + 255) & ~(size_t)255;
    unsigned short* R1 = (unsigned short*)(ws + off); off += (size_t)MROWS * 1024 * 2;          // Kb -> x1
    unsigned short* R2 = (unsigned short*)(ws + off); off += (size_t)512 * 64 * NPADV * 2;      // Vt -> h2
    unsigned short* R3 = (unsigned short*)(ws + off);                                           // fc1 out
    size_t rem = ws_size > off ? ws_size - off : 0;
    const int CH = rem >= (size_t)MROWS * H4DIM * 2 ? H4DIM
                 : (rem >= (size_t)MROWS * 1024 * 2 ? 1024
                 : (rem >= (size_t)MROWS * 512 * 2 ? 512 : 256));

    // d_out (f32 [M,1024] = 75.6MB) used as scratch: half1 = Qb, half2 = h1 then obuf
    unsigned short* Qb   = (unsigned short*)d_out;
    unsigned short* h1   = Qb + (size_t)MROWS * 1024;
    unsigned short* obuf = h1;
    unsigned short* Kb = R1;
    unsigned short* Vt = R2;
    unsigned short* x1 = R1;
    unsigned short* h2 = R2;

    // weight/bias conversion (every call; graph-safe)
    conv_kernel<<<3145728 / 1024, 256, 0, stream>>>(qkv_w,  qkvw_b,  3145728);
    conv_kernel<<<1048576 / 1024, 256, 0, stream>>>(proj_w, projw_b, 1048576);
    conv_kernel<<<4194304 / 1024, 256, 0, stream>>>(fc1_w,  fc1w_b,  4194304);
    conv_kernel<<<4194304 / 1024, 256, 0, stream>>>(fc2_w,  fc2w_b,  4194304);
    conv_kernel<<<3, 256, 0, stream>>>(qkv_b,  qkvb_b,  3072);
    conv_kernel<<<1, 256, 0, stream>>>(proj_b, projb_b, 1024);
    conv_kernel<<<4, 256, 0, stream>>>(fc1_b,  fc1b_b,  4096);
    conv_kernel<<<1, 256, 0, stream>>>(fc2_b,  fc2b_b,  1024);

    const int mt128 = (MROWS + 127) / 128;  // 145
    const int mt256 = (MROWS + 255) / 256;  // 73

    // h1 = LN1(x)
    ln_kernel<true><<<MROWS, 256, 0, stream>>>(x, ln1_w, ln1_b, h1);
    // qkv GEMM -> split Qb/Kb/Vt  (N=3072: 876 blocks)
    gemm256<0><<<(C3DIM / 256) * mt256, 512, 0, stream>>>(
        h1, qkvw_b, CDIM, qkvb_b, Qb, Kb, Vt, CDIM, C3DIM, C3DIM / 256);
    // attention -> obuf (overwrites h1; h1 dead)
    attn_kernel<<<5120, 256, 0, stream>>>(Qb, Kb, Vt, obuf);
    // x1 = bf16(x + obuf @ proj_w^T + proj_b)
    gemm128<1><<<(CDIM / 128) * mt128, 256, 0, stream>>>(
        obuf, projw_b, CDIM, projb_b, x, x1, CDIM, CDIM, CDIM / 128);
    // h2 = LN2(x1)   (Vt dead)
    ln_kernel<false><<<MROWS, 256, 0, stream>>>(x1, ln2_w, ln2_b, h2);

    if (CH == H4DIM) {
        // fc1 (N=4096: 1168 blocks)
        gemm256<2><<<(H4DIM / 256) * mt256, 512, 0, stream>>>(
            h2, fc1w_b, CDIM, fc1b_b, R3, nullptr, nullptr, CDIM, H4DIM, H4DIM / 256);
        // fc2 (A = 151 MB R3; XCD-chunked + depth-2 pipeline)
        gemm128<3><<<(CDIM / 128) * mt128, 256, 0, stream>>>(
            R3, fc2w_b, H4DIM, fc2b_b, x1, d_out, H4DIM, CDIM, CDIM / 128);
    } else {
        for (int c0 = 0; c0 < H4DIM; c0 += CH) {
            gemm256<2><<<(CH / 256) * mt256, 512, 0, stream>>>(
                h2, fc1w_b + (size_t)c0 * CDIM, CDIM, fc1b_b + c0, R3, nullptr, nullptr, CDIM, CH, CH / 256);
            if (c0 == 0)
                gemm128<3><<<(CDIM / 128) * mt128, 256, 0, stream>>>(
                    R3, fc2w_b, H4DIM, fc2b_b, x1, d_out, CH, CDIM, CDIM / 128);
            else
                gemm128<4><<<(CDIM / 128) * mt128, 256, 0, stream>>>(
                    R3, fc2w_b + c0, H4DIM, nullptr, nullptr, d_out, CH, CDIM, CDIM / 128);
        }
    }
}